// Round 10
// baseline (10537.357 us; speedup 1.0000x reference)
//
#include <hip/hip_runtime.h>

#define NNZC   1000000
#define NPOI   100000
#define NEDGE  50000
#define NUSER  50000
#define DIM    128
#define NL     3

#define PB     64          // chunks per matrix for hist/scatter passes (NNZC/PB = 15625)
#define BSH    7           // 128-row buckets (uniform; bucket = LDS-accum tile of push-spmm)
#define BROWS  128
#define ROWPAD 132         // floats per row in LDS acc: 132%32=4 -> rows rotate banks
#define NBKT   782         // ceil(100000/128); 50k matrices use buckets 0..390 (rest empty)
#define SCANN  (4 * NBKT * PB)   // 200192 row counters (+1 sentinel)
#define NCB    49          // col-buckets per matrix (col>>cshift)
#define SCANC  (4 * NCB * PB)    // 12544 col counters (+1 sentinel)

static inline int ceil_div(int a, int b) { return (a + b - 1) / b; }

typedef unsigned int uint32;

// ---- bf16 helpers: rows stored as packed pairs (uint32 = 2 bf16, little-endian) ----
__device__ __forceinline__ float bfLO(uint32 u) { return __uint_as_float(u << 16); }
__device__ __forceinline__ float bfHI(uint32 u) { return __uint_as_float(u & 0xffff0000u); }
__device__ __forceinline__ uint32 bf16_rne(float f) {
    uint32 u = __float_as_uint(f);
    return (u + 0x7fffu + ((u >> 16) & 1u)) >> 16;
}
__device__ __forceinline__ uint32 bfPACK(float a, float b) {
    return bf16_rne(a) | (bf16_rne(b) << 16);
}
// ---- packed entry: vals uniform [0,1) -> sign bit 0 -> 15-bit bf16; col fits 17 bits.
__device__ __forceinline__ uint32 csrPACK(int col, float val) {
    return ((uint32)col) | (bf16_rne(val) << 17);
}
__device__ __forceinline__ int   csrCOL(uint32 e) { return (int)(e & 0x1FFFFu); }
__device__ __forceinline__ float csrVAL(uint32 e) { return __uint_as_float((e >> 17) << 16); }

// per-matrix constants: tar(0), src(1), up(2), pu(3)
__device__ __constant__ const int c_cshift[4] = { 11, 10, 11, 10 };  // col-bucket: 2048/1024 cols

// ====== build: col-sort -> row-bucket sort (counting passes, no global atomics) ======
// INVARIANT (round-7 lesson): every histogram is taken over EXACTLY the sequence its
// scatter consumes (row histogram reads rec1, not r[]).
// rec2 = entries grouped by (matrix, 128-row bucket), col-window-ordered inside each
// bucket -- consumed DIRECTLY by the push-spmm (no ELL materialization).

__global__ __launch_bounds__(1024) void colHist_kernel(
    const int* __restrict__ c0, const int* __restrict__ c1,
    const int* __restrict__ c2, const int* __restrict__ c3,
    int* __restrict__ histC) {
    __shared__ int h[NCB];
    int m = blockIdx.y, p = blockIdx.x;
    for (int i = threadIdx.x; i < NCB; i += 1024) h[i] = 0;
    __syncthreads();
    const int* c = (m == 0) ? c0 : (m == 1) ? c1 : (m == 2) ? c2 : c3;
    int shift = c_cshift[m];
    int lo = (int)(((long long)NNZC * p) >> 6);
    int hi = (int)(((long long)NNZC * (p + 1)) >> 6);
    for (int i = lo + (int)threadIdx.x; i < hi; i += 1024)
        atomicAdd(&h[c[i] >> shift], 1);
    __syncthreads();
    for (int b = threadIdx.x; b < NCB; b += 1024)
        histC[(m * NCB + b) * PB + p] = h[b];
}

// exclusive scan of N counters (compile-time N; sentinel total at g[N])
template<int N>
__global__ __launch_bounds__(256) void scan_kernel(int* __restrict__ g) {
    constexpr int CHUNK = N / 256;
    __shared__ int wsum[4];
    int t = threadIdx.x;
    int lane = t & 63, wid = t >> 6;
    int lo = t * CHUNK;
    int s = 0;
#pragma unroll 8
    for (int i = 0; i < CHUNK; i++) s += g[lo + i];
    int incl = s;
#pragma unroll
    for (int d = 1; d < 64; d <<= 1) {
        int x = __shfl_up(incl, d);
        if (lane >= d) incl += x;
    }
    if (lane == 63) wsum[wid] = incl;
    __syncthreads();
    if (t == 0) {
        int a = 0;
        for (int w = 0; w < 4; w++) { int x = wsum[w]; wsum[w] = a; a += x; }
    }
    __syncthreads();
    int off = wsum[wid] + incl - s;
#pragma unroll 8
    for (int i = 0; i < CHUNK; i++) { int v = g[lo + i]; g[lo + i] = off; off += v; }
    if (t == 255) g[N] = off;
}

__global__ __launch_bounds__(1024) void colScat_kernel(
    const int* __restrict__ r0, const int* __restrict__ r1,
    const int* __restrict__ r2, const int* __restrict__ r3,
    const int* __restrict__ c0, const int* __restrict__ c1,
    const int* __restrict__ c2, const int* __restrict__ c3,
    const float* __restrict__ v0, const float* __restrict__ v1,
    const float* __restrict__ v2, const float* __restrict__ v3,
    const int* __restrict__ scanC, uint2* __restrict__ rec1) {
    __shared__ int cur[NCB];
    int m = blockIdx.y, p = blockIdx.x;
    for (int b = threadIdx.x; b < NCB; b += 1024)
        cur[b] = scanC[(m * NCB + b) * PB + p];
    __syncthreads();
    const int*   r = (m == 0) ? r0 : (m == 1) ? r1 : (m == 2) ? r2 : r3;
    const int*   c = (m == 0) ? c0 : (m == 1) ? c1 : (m == 2) ? c2 : c3;
    const float* v = (m == 0) ? v0 : (m == 1) ? v1 : (m == 2) ? v2 : v3;
    int shift = c_cshift[m];
    int lo = (int)(((long long)NNZC * p) >> 6);
    int hi = (int)(((long long)NNZC * (p + 1)) >> 6);
    for (int i = lo + (int)threadIdx.x; i < hi; i += 1024) {
        int col = c[i];
        int pos = atomicAdd(&cur[col >> shift], 1);
        rec1[pos] = make_uint2((uint32)r[i], csrPACK(col, v[i]));
    }
}

// row-bucket histogram over rec1 IN REC1 ORDER
__global__ __launch_bounds__(1024) void histR_kernel(
    const uint2* __restrict__ rec1, int* __restrict__ histG) {
    __shared__ int h[NBKT];
    int m = blockIdx.y, p = blockIdx.x;
    for (int i = threadIdx.x; i < NBKT; i += 1024) h[i] = 0;
    __syncthreads();
    const uint2* rin = rec1 + (size_t)m * NNZC;
    int lo = (int)(((long long)NNZC * p) >> 6);
    int hi = (int)(((long long)NNZC * (p + 1)) >> 6);
    for (int i = lo + (int)threadIdx.x; i < hi; i += 1024)
        atomicAdd(&h[(int)rin[i].x >> BSH], 1);
    __syncthreads();
    for (int b = threadIdx.x; b < NBKT; b += 1024)
        histG[(m * NBKT + b) * PB + p] = h[b];
}

// row-bucket scatter consuming rec1 sequentially (col-sorted) -> rec2 buckets are
// col-window-ordered inside.
__global__ __launch_bounds__(1024) void scatS_kernel(
    const uint2* __restrict__ rec1, const int* __restrict__ scanG,
    uint2* __restrict__ rec2) {
    __shared__ int cur[NBKT];
    int m = blockIdx.y, p = blockIdx.x;
    for (int b = threadIdx.x; b < NBKT; b += 1024)
        cur[b] = scanG[(m * NBKT + b) * PB + p];
    __syncthreads();
    const uint2* rin = rec1 + (size_t)m * NNZC;
    int lo = (int)(((long long)NNZC * p) >> 6);
    int hi = (int)(((long long)NNZC * (p + 1)) >> 6);
    for (int i = lo + (int)threadIdx.x; i < hi; i += 1024) {
        uint2 e = rin[i];
        int pos = atomicAdd(&cur[(int)e.x >> BSH], 1);
        rec2[pos] = e;
    }
}

// ---------------- softmax over the two 4-element attention vectors ----------------
__global__ void softmax4_kernel(const float* __restrict__ adi,
                                const float* __restrict__ amv,
                                float* __restrict__ w) {
    if (blockIdx.x == 0 && threadIdx.x == 0) {
        for (int b = 0; b < 2; b++) {
            const float* a = b ? amv : adi;
            float m = a[0];
            for (int l = 1; l < 4; l++) m = fmaxf(m, a[l]);
            float e[4]; float s = 0.f;
            for (int l = 0; l < 4; l++) { e[l] = __expf(a[l] - m); s += e[l]; }
            for (int l = 0; l < 4; l++) w[b * 4 + l] = e[l] / s;
        }
    }
}

// ---------------- fp32 -> packed bf16 cast (pois) ----------------
__global__ void cast_bf16_kernel(const float* __restrict__ src, uint32* __restrict__ dst, int npairs) {
    int i = blockIdx.x * blockDim.x + threadIdx.x;
    if (i < npairs) {
        float2 f = *(const float2*)(src + (size_t)i * 2);
        dst[i] = bfPACK(f.x, f.y);
    }
}

// ================= push-SpMM: block = 128-row LDS fp32 tile, entries from rec2 ======
// 16-lane group per entry: lane t gathers uint4 (16B) of x[col], does 8 LDS atomicAdds
// into acc[row][t*8..].  All blocks walk equal-length col-sorted streams in lock-step
// -> machine-wide operand window ~1 col-bucket (~0.5MB) -> L2-resident gathers.
template<int RESID>
__global__ __launch_bounds__(512) void spmmP_kernel(
    const uint2* __restrict__ rec, const int* __restrict__ scanG, int mtx,
    const uint32* __restrict__ xbf, const uint32* __restrict__ xinbf,
    uint32* __restrict__ ybf, int n_rows) {
    __shared__ float acc[BROWS * ROWPAD];
    int b = (int)blockIdx.x;
    int rowlo = b << BSH;
    int tid = (int)threadIdx.x;
    for (int i = tid; i < BROWS * ROWPAD; i += 512) acc[i] = 0.f;
    __syncthreads();
    int lo = scanG[(mtx * NBKT + b) * PB];
    int hi = scanG[(mtx * NBKT + b + 1) * PB];   // mtx=3,b=781 -> scanG[SCANN] sentinel
    int g = tid >> 4, t = tid & 15;

#define PSH_ONE(E, U) do {                                               \
        float _v = csrVAL((E).y);                                        \
        float* _a = acc + ((int)(E).x - rowlo) * ROWPAD + t * 8;         \
        atomicAdd(_a + 0, _v * bfLO((U).x));                             \
        atomicAdd(_a + 1, _v * bfHI((U).x));                             \
        atomicAdd(_a + 2, _v * bfLO((U).y));                             \
        atomicAdd(_a + 3, _v * bfHI((U).y));                             \
        atomicAdd(_a + 4, _v * bfLO((U).z));                             \
        atomicAdd(_a + 5, _v * bfHI((U).z));                             \
        atomicAdd(_a + 6, _v * bfLO((U).w));                             \
        atomicAdd(_a + 7, _v * bfHI((U).w));                             \
    } while (0)

    int i = lo + g;
    for (; i + 32 < hi; i += 64) {
        uint2 e0 = rec[i], e1 = rec[i + 32];
        uint4 u0 = *((const uint4*)(xbf + (size_t)csrCOL(e0.y) * 64) + t);
        uint4 u1 = *((const uint4*)(xbf + (size_t)csrCOL(e1.y) * 64) + t);
        PSH_ONE(e0, u0);
        PSH_ONE(e1, u1);
    }
    if (i < hi) {
        uint2 e0 = rec[i];
        uint4 u0 = *((const uint4*)(xbf + (size_t)csrCOL(e0.y) * 64) + t);
        PSH_ONE(e0, u0);
    }
#undef PSH_ONE
    __syncthreads();
    // epilogue: group g writes rows g, g+32, g+64, g+96 (16B per lane, coalesced)
    for (int k = 0; k < BROWS; k += 32) {
        int rl = g + k;
        int row = rowlo + rl;
        if (row >= n_rows) break;   // rows increase with k per thread
        const float* a = acc + rl * ROWPAD + t * 8;
        uint4 o;
        if (RESID) {
            uint4 ui = *((const uint4*)(xinbf + (size_t)row * 64) + t);
            o.x = bfPACK(fmaxf(a[0], 0.f) + bfLO(ui.x), fmaxf(a[1], 0.f) + bfHI(ui.x));
            o.y = bfPACK(fmaxf(a[2], 0.f) + bfLO(ui.y), fmaxf(a[3], 0.f) + bfHI(ui.y));
            o.z = bfPACK(fmaxf(a[4], 0.f) + bfLO(ui.z), fmaxf(a[5], 0.f) + bfHI(ui.z));
            o.w = bfPACK(fmaxf(a[6], 0.f) + bfLO(ui.w), fmaxf(a[7], 0.f) + bfHI(ui.w));
        } else {
            o.x = bfPACK(a[0], a[1]); o.y = bfPACK(a[2], a[3]);
            o.z = bfPACK(a[4], a[5]); o.w = bfPACK(a[6], a[7]);
        }
        *((uint4*)(ybf + (size_t)row * 64) + t) = o;
    }
}

// ---------------- epilogues: out = (w0di+w0mv)*pois + sum_l w_l * x_l ----------------
__global__ void epi1_kernel(const float* __restrict__ pois,
                            const uint32* __restrict__ x1, const uint32* __restrict__ x2,
                            const uint32* __restrict__ x3, const float* __restrict__ w,
                            float* __restrict__ out) {
    int i = blockIdx.x * blockDim.x + threadIdx.x;
    if (i < NPOI * 64) {
        float w0 = w[0] + w[4];
        float2 pf = ((const float2*)pois)[i];
        uint32 u1 = x1[i], u2 = x2[i], u3 = x3[i];
        float o0 = w0 * pf.x + w[1] * bfLO(u1) + w[2] * bfLO(u2) + w[3] * bfLO(u3);
        float o1 = w0 * pf.y + w[1] * bfHI(u1) + w[2] * bfHI(u2) + w[3] * bfHI(u3);
        ((float2*)out)[i] = make_float2(o0, o1);
    }
}

__global__ void epi2_kernel(const uint32* __restrict__ x1, const uint32* __restrict__ x2,
                            const uint32* __restrict__ x3, const float* __restrict__ w,
                            float* __restrict__ out) {
    int i = blockIdx.x * blockDim.x + threadIdx.x;
    if (i < NPOI * 64) {
        uint32 u1 = x1[i], u2 = x2[i], u3 = x3[i];
        float2 ov = ((float2*)out)[i];
        ov.x += w[5] * bfLO(u1) + w[6] * bfLO(u2) + w[7] * bfLO(u3);
        ov.y += w[5] * bfHI(u1) + w[6] * bfHI(u2) + w[7] * bfHI(u3);
        ((float2*)out)[i] = ov;
    }
}

extern "C" void kernel_launch(void* const* d_in, const int* in_sizes, int n_in,
                              void* d_out, int out_size, void* d_ws, size_t ws_size,
                              hipStream_t stream) {
    const float* pois = (const float*)d_in[0];
    const int*   rows_in[4] = { (const int*)d_in[1], (const int*)d_in[4],
                                (const int*)d_in[7], (const int*)d_in[10] };
    const int*   cols_in[4] = { (const int*)d_in[2], (const int*)d_in[5],
                                (const int*)d_in[8], (const int*)d_in[11] };
    const float* vals_in[4] = { (const float*)d_in[3], (const float*)d_in[6],
                                (const float*)d_in[9], (const float*)d_in[12] };
    const float* attn_di = (const float*)d_in[13];
    const float* attn_mv = (const float*)d_in[14];
    float* out = (float*)d_out;

    // -------- workspace carve-up (~148 MB) --------
    char* p = (char*)d_ws;
    float*  wsoft      = (float*)p;  p += 256;
    int*    scanG      = (int*)p;    p += (size_t)(SCANN + 64) * 4;  // ~801 KB
    p = (char*)(((size_t)p + 255) & ~255ull);
    int*    scanC      = (int*)p;    p += (size_t)(SCANC + 64) * 4;  // ~50 KB
    p = (char*)(((size_t)p + 255) & ~255ull);
    uint2*  rec2       = (uint2*)p;  p += (size_t)4 * NNZC * 8;      // 32 MB, lives whole run
    uint32* mbf        = (uint32*)p; p += (size_t)NEDGE * 64 * 4;    // 12.8 MB
    uint32* poisbf     = (uint32*)p; p += (size_t)NPOI * 64 * 4;     // 25.6 MB
    uint32* xl[3];
    for (int l = 0; l < 3; l++) { xl[l] = (uint32*)p; p += (size_t)NPOI * 64 * 4; }
    // rec1 (32 MB) aliases xl[0..1] (51.2 MB): fully consumed by scatS before spmms run.
    uint2* rec1 = (uint2*)xl[0];
    (void)ws_size; (void)out_size; (void)n_in; (void)in_sizes;

    // -------- build: col-sort -> row-hist(rec1) -> row-bucket sort --------
    colHist_kernel<<<dim3(PB, 4), 1024, 0, stream>>>(
        cols_in[0], cols_in[1], cols_in[2], cols_in[3], scanC);
    scan_kernel<SCANC><<<1, 256, 0, stream>>>(scanC);
    colScat_kernel<<<dim3(PB, 4), 1024, 0, stream>>>(
        rows_in[0], rows_in[1], rows_in[2], rows_in[3],
        cols_in[0], cols_in[1], cols_in[2], cols_in[3],
        vals_in[0], vals_in[1], vals_in[2], vals_in[3],
        scanC, rec1);
    histR_kernel<<<dim3(PB, 4), 1024, 0, stream>>>(rec1, scanG);
    scan_kernel<SCANN><<<1, 256, 0, stream>>>(scanG);
    scatS_kernel<<<dim3(PB, 4), 1024, 0, stream>>>(rec1, scanG, rec2);

    // -------- attention weights + bf16 cast of pois --------
    softmax4_kernel<<<1, 64, 0, stream>>>(attn_di, attn_mv, wsoft);
    cast_bf16_kernel<<<ceil_div(NPOI * 64, 256), 256, 0, stream>>>(pois, poisbf, NPOI * 64);

    // -------- two branches, 3 layers each; epilogue per branch --------
    const int nb1 = ceil_div(NEDGE, BROWS);   // 391 buckets (hop1 targets 50k rows)
    const int nb2 = ceil_div(NPOI, BROWS);    // 782 buckets (hop2 targets 100k rows)
    for (int br = 0; br < 2; br++) {
        int m1i = br ? 2 : 0;   // up  : tar   (50k rows)
        int m2i = br ? 3 : 1;   // pu  : src   (100k rows)
        const uint32* xcur = poisbf;
        for (int l = 1; l <= NL; l++) {
            spmmP_kernel<0><<<nb1, 512, 0, stream>>>(
                rec2, scanG, m1i, xcur, (const uint32*)nullptr, mbf, NEDGE);
            spmmP_kernel<1><<<nb2, 512, 0, stream>>>(
                rec2, scanG, m2i, mbf, xcur, xl[l - 1], NPOI);
            xcur = xl[l - 1];
        }
        if (br == 0)
            epi1_kernel<<<ceil_div(NPOI * 64, 256), 256, 0, stream>>>(
                pois, xl[0], xl[1], xl[2], wsoft, out);
        else
            epi2_kernel<<<ceil_div(NPOI * 64, 256), 256, 0, stream>>>(
                xl[0], xl[1], xl[2], wsoft, out);
    }
}

// Round 11
// 763.186 us; speedup vs baseline: 13.8071x; 13.8071x over previous
//
#include <hip/hip_runtime.h>

#define NNZC   1000000
#define NPOI   100000
#define NEDGE  50000
#define NUSER  50000
#define DIM    128
#define NL     3

#define PB     64          // chunks per matrix (PB=128 regressed: short runs re-amplified writes)
#define NBKT   196         // row-buckets per matrix (rows>>shift, shift 8 or 9 -> max bucket 195)
#define SCANN  (4 * NBKT * PB)   // 50176 counters (+1 sentinel)

static inline int ceil_div(int a, int b) { return (a + b - 1) / b; }

typedef unsigned int uint32;

// ---- bf16 helpers: rows stored as packed pairs (uint32 = 2 bf16, little-endian) ----
__device__ __forceinline__ float bfLO(uint32 u) { return __uint_as_float(u << 16); }
__device__ __forceinline__ float bfHI(uint32 u) { return __uint_as_float(u & 0xffff0000u); }
__device__ __forceinline__ uint32 bf16_rne(float f) {
    uint32 u = __float_as_uint(f);
    return (u + 0x7fffu + ((u >> 16) & 1u)) >> 16;
}
__device__ __forceinline__ uint32 bfPACK(float a, float b) {
    return bf16_rne(a) | (bf16_rne(b) << 16);
}
// ---- packed ELL entry: vals uniform [0,1) -> sign bit 0 -> 15-bit bf16; col fits 17 bits.
// entry 0 == (col 0, val +0.0) -> usable as an exact no-op pad.
__device__ __forceinline__ uint32 csrPACK(int col, float val) {
    return ((uint32)col) | (bf16_rne(val) << 17);
}
__device__ __forceinline__ int   csrCOL(uint32 e) { return (int)(e & 0x1FFFFu); }
__device__ __forceinline__ float csrVAL(uint32 e) { return __uint_as_float((e >> 17) << 16); }

// per-matrix constants: tar(0), src(1), up(2), pu(3)
__device__ __constant__ const int c_nrows[4]  = { NEDGE, NPOI, NUSER, NPOI };
__device__ __constant__ const int c_cntoff[4] = { 0, NEDGE, NEDGE + NPOI, NEDGE + NPOI + NUSER };
__device__ __constant__ const int c_cap[4]    = { 64, 48, 64, 48 };
__device__ __constant__ const int c_shift[4]  = { 8, 9, 8, 9 };   // rows-per-bucket 256 / 512
__device__ __constant__ const long long c_elloff[4] = { 0, 3200000, 8000000, 11200000 };
// total ELL entries = 16,000,000 (64 MB)

// =============== ELL build: bucketed counting sort (4 passes, no global atomics) ===============

// Pass H: per-(matrix, chunk) histogram over row-buckets.  histG[(m*NBKT+b)*PB + p]
__global__ __launch_bounds__(1024) void histH_kernel(
    const int* __restrict__ r0, const int* __restrict__ r1,
    const int* __restrict__ r2, const int* __restrict__ r3,
    int* __restrict__ histG) {
    __shared__ int h[NBKT];
    int m = blockIdx.y, p = blockIdx.x;
    for (int i = threadIdx.x; i < NBKT; i += 1024) h[i] = 0;
    __syncthreads();
    const int* r = (m == 0) ? r0 : (m == 1) ? r1 : (m == 2) ? r2 : r3;
    int shift = c_shift[m];
    int lo = (int)(((long long)NNZC * p) >> 6);        // PB == 64
    int hi = (int)(((long long)NNZC * (p + 1)) >> 6);
    for (int i = lo + (int)threadIdx.x; i < hi; i += 1024)
        atomicAdd(&h[r[i] >> shift], 1);
    __syncthreads();
    for (int b = threadIdx.x; b < NBKT; b += 1024)
        histG[(m * NBKT + b) * PB + p] = h[b];
}

// Pass X: in-place exclusive scan of the 50176 counters (+ sentinel total at [SCANN]).
// Compile-time trip count (round-8 lesson: runtime trip count -> no unroll -> 88us).
__global__ __launch_bounds__(256) void scan_kernel(int* __restrict__ g) {
    __shared__ int base[257];
    int t = threadIdx.x;
    const int chunk = SCANN / 256;   // 196
    int lo = t * chunk;
    int s = 0;
    for (int i = 0; i < chunk; i++) s += g[lo + i];
    base[t + 1] = s;
    __syncthreads();
    if (t == 0) {
        base[0] = 0;
        for (int i = 1; i <= 256; i++) base[i] += base[i - 1];
    }
    __syncthreads();
    int off = base[t];
    for (int i = 0; i < chunk; i++) { int v = g[lo + i]; g[lo + i] = off; off += v; }
    if (t == 255) g[SCANN] = base[256];
}

// Pass S: scatter (row, packed entry) records into exclusive dense ranges (bucket-major).
__global__ __launch_bounds__(1024) void scatS_kernel(
    const int* __restrict__ r0, const int* __restrict__ r1,
    const int* __restrict__ r2, const int* __restrict__ r3,
    const int* __restrict__ c0, const int* __restrict__ c1,
    const int* __restrict__ c2, const int* __restrict__ c3,
    const float* __restrict__ v0, const float* __restrict__ v1,
    const float* __restrict__ v2, const float* __restrict__ v3,
    const int* __restrict__ scanG, uint2* __restrict__ rec) {
    __shared__ int cur[NBKT];
    int m = blockIdx.y, p = blockIdx.x;
    for (int b = threadIdx.x; b < NBKT; b += 1024)
        cur[b] = scanG[(m * NBKT + b) * PB + p];
    __syncthreads();
    const int*   r = (m == 0) ? r0 : (m == 1) ? r1 : (m == 2) ? r2 : r3;
    const int*   c = (m == 0) ? c0 : (m == 1) ? c1 : (m == 2) ? c2 : c3;
    const float* v = (m == 0) ? v0 : (m == 1) ? v1 : (m == 2) ? v2 : v3;
    int shift = c_shift[m];
    int lo = (int)(((long long)NNZC * p) >> 6);
    int hi = (int)(((long long)NNZC * (p + 1)) >> 6);
    for (int i = lo + (int)threadIdx.x; i < hi; i += 1024) {
        int row = r[i];
        int pos = atomicAdd(&cur[row >> shift], 1);
        rec[pos] = make_uint2((uint32)row, csrPACK(c[i], v[i]));
    }
}

// Pass B: one block per (matrix, bucket).  Bucket rows are block-exclusive -> LDS row
// counters; ELL scatter confined to a 64-96 KB L2-resident region.  NEW: zero-pad each
// row's slots [cnt, ceil8(cnt)) so the spmm runs one uniform 8-wide loop (no serial tail).
__global__ __launch_bounds__(512) void fillB_kernel(
    const int* __restrict__ scanG, const uint2* __restrict__ rec,
    int* __restrict__ counts_all, uint32* __restrict__ ell) {
    __shared__ int cnt[512];
    int bx = (int)blockIdx.x;
    int m = bx / NBKT, b = bx - m * NBKT;
    int shift = c_shift[m];
    int rowlo = b << shift;
    int bklen = 1 << shift;
    for (int i = threadIdx.x; i < bklen; i += 512) cnt[i] = 0;
    __syncthreads();
    int lo = scanG[(m * NBKT + b) * PB];
    int hi = scanG[(m * NBKT + b + 1) * PB];   // b=195,m=3 -> scanG[SCANN] sentinel
    int cap = c_cap[m];
    uint32* ebase = ell + c_elloff[m];
    for (int i = lo + (int)threadIdx.x; i < hi; i += 512) {
        uint2 e = rec[i];
        int row = (int)e.x;
        int pos = atomicAdd(&cnt[row - rowlo], 1);
        ebase[(size_t)row * cap + pos] = e.y;
    }
    __syncthreads();
    int nrows_b = c_nrows[m] - rowlo;
    if (nrows_b > bklen) nrows_b = bklen;
    int* counts = counts_all + c_cntoff[m];
    for (int i = threadIdx.x; i < nrows_b; i += 512) {
        int ci = cnt[i];
        counts[rowlo + i] = ci;
        int pad = (ci + 7) & ~7;               // <= cap (cap is a multiple of 8)
        uint32* erow = ebase + (size_t)(rowlo + i) * cap;
        for (int j = ci; j < pad; j++) erow[j] = 0;   // exact no-op entries
    }
}

// ---------------- softmax over the two 4-element attention vectors ----------------
__global__ void softmax4_kernel(const float* __restrict__ adi,
                                const float* __restrict__ amv,
                                float* __restrict__ w) {
    if (blockIdx.x == 0 && threadIdx.x == 0) {
        for (int b = 0; b < 2; b++) {
            const float* a = b ? amv : adi;
            float m = a[0];
            for (int l = 1; l < 4; l++) m = fmaxf(m, a[l]);
            float e[4]; float s = 0.f;
            for (int l = 0; l < 4; l++) { e[l] = __expf(a[l] - m); s += e[l]; }
            for (int l = 0; l < 4; l++) w[b * 4 + l] = e[l] / s;
        }
    }
}

// ---------------- fp32 -> packed bf16 cast (pois) ----------------
__global__ void cast_bf16_kernel(const float* __restrict__ src, uint32* __restrict__ dst, int npairs) {
    int i = blockIdx.x * blockDim.x + threadIdx.x;
    if (i < npairs) {
        float2 f = *(const float2*)(src + (size_t)i * 2);
        dst[i] = bfPACK(f.x, f.y);
    }
}

// ---- 8-FMA helper: one scalar entry value v against a 16B (8 bf16) operand slice ----
__device__ __forceinline__ void fma8(float2& a0, float2& a1, float2& a2, float2& a3,
                                     float v, uint4 u) {
    a0.x = fmaf(v, bfLO(u.x), a0.x); a0.y = fmaf(v, bfHI(u.x), a0.y);
    a1.x = fmaf(v, bfLO(u.y), a1.x); a1.y = fmaf(v, bfHI(u.y), a1.y);
    a2.x = fmaf(v, bfLO(u.z), a2.x); a2.y = fmaf(v, bfHI(u.z), a2.y);
    a3.x = fmaf(v, bfLO(u.w), a3.x); a3.y = fmaf(v, bfHI(u.w), a3.y);
}

// ---------------- hop1 SpMM: y_bf[row] = A @ x_bf ----------------
// 16-lane group per row: lane t gathers uint4 (16B = 8 bf16) of the 256B operand row.
// Single uniform 8-wide loop over the zero-padded count: no 4-loop, no serial scalar
// tail (pad entries are exact no-ops), 8 gathers always in flight.
template<int CAP>
__global__ __launch_bounds__(256) void spmm1_kernel(
    const int* __restrict__ counts, const uint32* __restrict__ ell,
    const uint32* __restrict__ xbf, uint32* __restrict__ ybf, int n_rows) {
    int row = (int)((blockIdx.x * blockDim.x + threadIdx.x) >> 4);
    int t   = (int)(threadIdx.x & 15);
    if (row >= n_rows) return;
    int pad = (counts[row] + 7) & ~7;
    const uint32* erow = ell + (size_t)row * CAP;
    float2 a0 = {0.f,0.f}, a1 = {0.f,0.f}, a2 = {0.f,0.f}, a3 = {0.f,0.f};
    for (int j = 0; j < pad; j += 8) {
        uint4 qa = *(const uint4*)(erow + j);
        uint4 qb = *(const uint4*)(erow + j + 4);
        uint4 u0 = *((const uint4*)(xbf + (size_t)csrCOL(qa.x) * 64) + t);
        uint4 u1 = *((const uint4*)(xbf + (size_t)csrCOL(qa.y) * 64) + t);
        uint4 u2 = *((const uint4*)(xbf + (size_t)csrCOL(qa.z) * 64) + t);
        uint4 u3 = *((const uint4*)(xbf + (size_t)csrCOL(qa.w) * 64) + t);
        uint4 u4 = *((const uint4*)(xbf + (size_t)csrCOL(qb.x) * 64) + t);
        uint4 u5 = *((const uint4*)(xbf + (size_t)csrCOL(qb.y) * 64) + t);
        uint4 u6 = *((const uint4*)(xbf + (size_t)csrCOL(qb.z) * 64) + t);
        uint4 u7 = *((const uint4*)(xbf + (size_t)csrCOL(qb.w) * 64) + t);
        fma8(a0,a1,a2,a3, csrVAL(qa.x), u0); fma8(a0,a1,a2,a3, csrVAL(qa.y), u1);
        fma8(a0,a1,a2,a3, csrVAL(qa.z), u2); fma8(a0,a1,a2,a3, csrVAL(qa.w), u3);
        fma8(a0,a1,a2,a3, csrVAL(qb.x), u4); fma8(a0,a1,a2,a3, csrVAL(qb.y), u5);
        fma8(a0,a1,a2,a3, csrVAL(qb.z), u6); fma8(a0,a1,a2,a3, csrVAL(qb.w), u7);
    }
    uint4 o;
    o.x = bfPACK(a0.x, a0.y); o.y = bfPACK(a1.x, a1.y);
    o.z = bfPACK(a2.x, a2.y); o.w = bfPACK(a3.x, a3.y);
    *((uint4*)(ybf + (size_t)row * 64) + t) = o;
}

// ---------------- hop2: xnew = relu(A@m)+xin, bf16 in/out, padded ELL ----------------
template<int CAP>
__global__ __launch_bounds__(256) void spmm2_kernel(
    const int* __restrict__ counts, const uint32* __restrict__ ell,
    const uint32* __restrict__ mbf, const uint32* __restrict__ xinbf,
    uint32* __restrict__ xoutbf, int n_rows) {
    int row = (int)((blockIdx.x * blockDim.x + threadIdx.x) >> 4);
    int t   = (int)(threadIdx.x & 15);
    if (row >= n_rows) return;
    int pad = (counts[row] + 7) & ~7;
    const uint32* erow = ell + (size_t)row * CAP;
    float2 a0 = {0.f,0.f}, a1 = {0.f,0.f}, a2 = {0.f,0.f}, a3 = {0.f,0.f};
    for (int j = 0; j < pad; j += 8) {
        uint4 qa = *(const uint4*)(erow + j);
        uint4 qb = *(const uint4*)(erow + j + 4);
        uint4 u0 = *((const uint4*)(mbf + (size_t)csrCOL(qa.x) * 64) + t);
        uint4 u1 = *((const uint4*)(mbf + (size_t)csrCOL(qa.y) * 64) + t);
        uint4 u2 = *((const uint4*)(mbf + (size_t)csrCOL(qa.z) * 64) + t);
        uint4 u3 = *((const uint4*)(mbf + (size_t)csrCOL(qa.w) * 64) + t);
        uint4 u4 = *((const uint4*)(mbf + (size_t)csrCOL(qb.x) * 64) + t);
        uint4 u5 = *((const uint4*)(mbf + (size_t)csrCOL(qb.y) * 64) + t);
        uint4 u6 = *((const uint4*)(mbf + (size_t)csrCOL(qb.z) * 64) + t);
        uint4 u7 = *((const uint4*)(mbf + (size_t)csrCOL(qb.w) * 64) + t);
        fma8(a0,a1,a2,a3, csrVAL(qa.x), u0); fma8(a0,a1,a2,a3, csrVAL(qa.y), u1);
        fma8(a0,a1,a2,a3, csrVAL(qa.z), u2); fma8(a0,a1,a2,a3, csrVAL(qa.w), u3);
        fma8(a0,a1,a2,a3, csrVAL(qb.x), u4); fma8(a0,a1,a2,a3, csrVAL(qb.y), u5);
        fma8(a0,a1,a2,a3, csrVAL(qb.z), u6); fma8(a0,a1,a2,a3, csrVAL(qb.w), u7);
    }
    uint4 ui = *((const uint4*)(xinbf + (size_t)row * 64) + t);
    uint4 o;
    o.x = bfPACK(fmaxf(a0.x, 0.f) + bfLO(ui.x), fmaxf(a0.y, 0.f) + bfHI(ui.x));
    o.y = bfPACK(fmaxf(a1.x, 0.f) + bfLO(ui.y), fmaxf(a1.y, 0.f) + bfHI(ui.y));
    o.z = bfPACK(fmaxf(a2.x, 0.f) + bfLO(ui.z), fmaxf(a2.y, 0.f) + bfHI(ui.z));
    o.w = bfPACK(fmaxf(a3.x, 0.f) + bfLO(ui.w), fmaxf(a3.y, 0.f) + bfHI(ui.w));
    *((uint4*)(xoutbf + (size_t)row * 64) + t) = o;
}

// ---------------- epilogues: out = (w0di+w0mv)*pois + sum_l w_l * x_l ----------------
__global__ void epi1_kernel(const float* __restrict__ pois,
                            const uint32* __restrict__ x1, const uint32* __restrict__ x2,
                            const uint32* __restrict__ x3, const float* __restrict__ w,
                            float* __restrict__ out) {
    int i = blockIdx.x * blockDim.x + threadIdx.x;
    if (i < NPOI * 64) {
        float w0 = w[0] + w[4];
        float2 pf = ((const float2*)pois)[i];
        uint32 u1 = x1[i], u2 = x2[i], u3 = x3[i];
        float o0 = w0 * pf.x + w[1] * bfLO(u1) + w[2] * bfLO(u2) + w[3] * bfLO(u3);
        float o1 = w0 * pf.y + w[1] * bfHI(u1) + w[2] * bfHI(u2) + w[3] * bfHI(u3);
        ((float2*)out)[i] = make_float2(o0, o1);
    }
}

__global__ void epi2_kernel(const uint32* __restrict__ x1, const uint32* __restrict__ x2,
                            const uint32* __restrict__ x3, const float* __restrict__ w,
                            float* __restrict__ out) {
    int i = blockIdx.x * blockDim.x + threadIdx.x;
    if (i < NPOI * 64) {
        uint32 u1 = x1[i], u2 = x2[i], u3 = x3[i];
        float2 ov = ((float2*)out)[i];
        ov.x += w[5] * bfLO(u1) + w[6] * bfLO(u2) + w[7] * bfLO(u3);
        ov.y += w[5] * bfHI(u1) + w[6] * bfHI(u2) + w[7] * bfHI(u3);
        ((float2*)out)[i] = ov;
    }
}

extern "C" void kernel_launch(void* const* d_in, const int* in_sizes, int n_in,
                              void* d_out, int out_size, void* d_ws, size_t ws_size,
                              hipStream_t stream) {
    const float* pois = (const float*)d_in[0];
    const int*   rows_in[4] = { (const int*)d_in[1], (const int*)d_in[4],
                                (const int*)d_in[7], (const int*)d_in[10] };
    const int*   cols_in[4] = { (const int*)d_in[2], (const int*)d_in[5],
                                (const int*)d_in[8], (const int*)d_in[11] };
    const float* vals_in[4] = { (const float*)d_in[3], (const float*)d_in[6],
                                (const float*)d_in[9], (const float*)d_in[12] };
    const float* attn_di = (const float*)d_in[13];
    const float* attn_mv = (const float*)d_in[14];
    float* out = (float*)d_out;

    const int NTOT = NEDGE + NPOI + NUSER + NPOI;  // 300000
    const int cnt_off[4] = { 0, NEDGE, NEDGE + NPOI, NEDGE + NPOI + NUSER };
    const long long ell_off[4] = { 0, 3200000, 8000000, 11200000 };

    // -------- workspace carve-up (~182 MB) --------
    char* p = (char*)d_ws;
    float*  wsoft      = (float*)p;  p += 256;
    int*    counts_all = (int*)p;    p += (size_t)NTOT * 4;
    p = (char*)(((size_t)p + 255) & ~255ull);
    int*    scanG      = (int*)p;    p += (size_t)(SCANN + 64) * 4;  // 50177 + pad
    p = (char*)(((size_t)p + 255) & ~255ull);
    uint32* ell        = (uint32*)p; p += (size_t)16000000 * 4;     // 64 MB ELL
    uint32* mbf        = (uint32*)p; p += (size_t)NEDGE * 64 * 4;   // 12.8 MB
    uint32* poisbf     = (uint32*)p; p += (size_t)NPOI * 64 * 4;    // 25.6 MB
    uint32* xl[3];
    for (int l = 0; l < 3; l++) { xl[l] = (uint32*)p; p += (size_t)NPOI * 64 * 4; }
    // records (32 MB) alias xl[0..1] (51.2 MB): consumed by fillB before spmm writes xl.
    uint2* rec = (uint2*)xl[0];
    (void)ws_size; (void)out_size; (void)n_in; (void)in_sizes;

    // -------- ELL build: hist -> scan -> scatter-sort -> bucket fill (+pad) --------
    histH_kernel<<<dim3(PB, 4), 1024, 0, stream>>>(
        rows_in[0], rows_in[1], rows_in[2], rows_in[3], scanG);
    scan_kernel<<<1, 256, 0, stream>>>(scanG);
    scatS_kernel<<<dim3(PB, 4), 1024, 0, stream>>>(
        rows_in[0], rows_in[1], rows_in[2], rows_in[3],
        cols_in[0], cols_in[1], cols_in[2], cols_in[3],
        vals_in[0], vals_in[1], vals_in[2], vals_in[3],
        scanG, rec);
    fillB_kernel<<<4 * NBKT, 512, 0, stream>>>(scanG, rec, counts_all, ell);

    // -------- attention weights + bf16 cast of pois --------
    softmax4_kernel<<<1, 64, 0, stream>>>(attn_di, attn_mv, wsoft);
    cast_bf16_kernel<<<ceil_div(NPOI * 64, 256), 256, 0, stream>>>(pois, poisbf, NPOI * 64);

    // -------- two branches, 3 layers each; epilogue per branch --------
    for (int br = 0; br < 2; br++) {
        int m1i = br ? 2 : 0;   // up  : tar   (50k rows, CAP 64)
        int m2i = br ? 3 : 1;   // pu  : src   (100k rows, CAP 48)
        const int* cn1 = counts_all + cnt_off[m1i];
        const int* cn2 = counts_all + cnt_off[m2i];
        const uint32* el1 = ell + ell_off[m1i];
        const uint32* el2 = ell + ell_off[m2i];
        const int n1 = 50000;  // NEDGE == NUSER
        const uint32* xcur = poisbf;
        for (int l = 1; l <= NL; l++) {
            spmm1_kernel<64><<<ceil_div(n1, 16), 256, 0, stream>>>(cn1, el1, xcur, mbf, n1);
            spmm2_kernel<48><<<ceil_div(NPOI, 16), 256, 0, stream>>>(
                cn2, el2, mbf, xcur, xl[l - 1], NPOI);
            xcur = xl[l - 1];
        }
        if (br == 0)
            epi1_kernel<<<ceil_div(NPOI * 64, 256), 256, 0, stream>>>(
                pois, xl[0], xl[1], xl[2], wsoft, out);
        else
            epi2_kernel<<<ceil_div(NPOI * 64, 256), 256, 0, stream>>>(
                xl[0], xl[1], xl[2], wsoft, out);
    }
}

// Round 12
// 736.025 us; speedup vs baseline: 14.3166x; 1.0369x over previous
//
#include <hip/hip_runtime.h>

#define NNZC   1000000
#define NPOI   100000
#define NEDGE  50000
#define NUSER  50000
#define DIM    128
#define NL     3

#define PB     64          // chunks per matrix (PB=128 regressed: short runs re-amplified writes)
#define NBKT   196         // row-buckets per matrix (rows>>shift, shift 8 or 9 -> max bucket 195)
#define SCANN  (4 * NBKT * PB)   // 50176 counters (+1 sentinel)

static inline int ceil_div(int a, int b) { return (a + b - 1) / b; }

typedef unsigned int uint32;

// ---- bf16 helpers: rows stored as packed pairs (uint32 = 2 bf16, little-endian) ----
__device__ __forceinline__ float bfLO(uint32 u) { return __uint_as_float(u << 16); }
__device__ __forceinline__ float bfHI(uint32 u) { return __uint_as_float(u & 0xffff0000u); }
__device__ __forceinline__ uint32 bf16_rne(float f) {
    uint32 u = __float_as_uint(f);
    return (u + 0x7fffu + ((u >> 16) & 1u)) >> 16;
}
__device__ __forceinline__ uint32 bfPACK(float a, float b) {
    return bf16_rne(a) | (bf16_rne(b) << 16);
}
// ---- packed ELL entry: vals uniform [0,1) -> sign bit 0 -> 15-bit bf16; col fits 17 bits.
// entry 0 == (col 0, val +0.0) -> usable as an exact no-op pad.
__device__ __forceinline__ uint32 csrPACK(int col, float val) {
    return ((uint32)col) | (bf16_rne(val) << 17);
}
__device__ __forceinline__ int   csrCOL(uint32 e) { return (int)(e & 0x1FFFFu); }
__device__ __forceinline__ float csrVAL(uint32 e) { return __uint_as_float((e >> 17) << 16); }

// per-matrix constants: tar(0), src(1), up(2), pu(3)
__device__ __constant__ const int c_nrows[4]  = { NEDGE, NPOI, NUSER, NPOI };
__device__ __constant__ const int c_cntoff[4] = { 0, NEDGE, NEDGE + NPOI, NEDGE + NPOI + NUSER };
__device__ __constant__ const int c_cap[4]    = { 64, 48, 64, 48 };
__device__ __constant__ const int c_shift[4]  = { 8, 9, 8, 9 };   // rows-per-bucket 256 / 512
__device__ __constant__ const long long c_elloff[4] = { 0, 3200000, 8000000, 11200000 };
// total ELL entries = 16,000,000 (64 MB)

// =============== ELL build: bucketed counting sort (4 passes, no global atomics) ===============

// Pass H: per-(matrix, chunk) histogram over row-buckets.  histG[(m*NBKT+b)*PB + p]
__global__ __launch_bounds__(1024) void histH_kernel(
    const int* __restrict__ r0, const int* __restrict__ r1,
    const int* __restrict__ r2, const int* __restrict__ r3,
    int* __restrict__ histG) {
    __shared__ int h[NBKT];
    int m = blockIdx.y, p = blockIdx.x;
    for (int i = threadIdx.x; i < NBKT; i += 1024) h[i] = 0;
    __syncthreads();
    const int* r = (m == 0) ? r0 : (m == 1) ? r1 : (m == 2) ? r2 : r3;
    int shift = c_shift[m];
    int lo = (int)(((long long)NNZC * p) >> 6);        // PB == 64
    int hi = (int)(((long long)NNZC * (p + 1)) >> 6);
    for (int i = lo + (int)threadIdx.x; i < hi; i += 1024)
        atomicAdd(&h[r[i] >> shift], 1);
    __syncthreads();
    for (int b = threadIdx.x; b < NBKT; b += 1024)
        histG[(m * NBKT + b) * PB + p] = h[b];
}

// Pass X: in-place exclusive scan of the 50176 counters (+ sentinel total at [SCANN]).
// Compile-time trip count (round-8 lesson: runtime trip count -> no unroll -> 88us).
__global__ __launch_bounds__(256) void scan_kernel(int* __restrict__ g) {
    __shared__ int base[257];
    int t = threadIdx.x;
    const int chunk = SCANN / 256;   // 196
    int lo = t * chunk;
    int s = 0;
    for (int i = 0; i < chunk; i++) s += g[lo + i];
    base[t + 1] = s;
    __syncthreads();
    if (t == 0) {
        base[0] = 0;
        for (int i = 1; i <= 256; i++) base[i] += base[i - 1];
    }
    __syncthreads();
    int off = base[t];
    for (int i = 0; i < chunk; i++) { int v = g[lo + i]; g[lo + i] = off; off += v; }
    if (t == 255) g[SCANN] = base[256];
}

// Pass S: scatter (row, packed entry) records into exclusive dense ranges (bucket-major).
__global__ __launch_bounds__(1024) void scatS_kernel(
    const int* __restrict__ r0, const int* __restrict__ r1,
    const int* __restrict__ r2, const int* __restrict__ r3,
    const int* __restrict__ c0, const int* __restrict__ c1,
    const int* __restrict__ c2, const int* __restrict__ c3,
    const float* __restrict__ v0, const float* __restrict__ v1,
    const float* __restrict__ v2, const float* __restrict__ v3,
    const int* __restrict__ scanG, uint2* __restrict__ rec) {
    __shared__ int cur[NBKT];
    int m = blockIdx.y, p = blockIdx.x;
    for (int b = threadIdx.x; b < NBKT; b += 1024)
        cur[b] = scanG[(m * NBKT + b) * PB + p];
    __syncthreads();
    const int*   r = (m == 0) ? r0 : (m == 1) ? r1 : (m == 2) ? r2 : r3;
    const int*   c = (m == 0) ? c0 : (m == 1) ? c1 : (m == 2) ? c2 : c3;
    const float* v = (m == 0) ? v0 : (m == 1) ? v1 : (m == 2) ? v2 : v3;
    int shift = c_shift[m];
    int lo = (int)(((long long)NNZC * p) >> 6);
    int hi = (int)(((long long)NNZC * (p + 1)) >> 6);
    for (int i = lo + (int)threadIdx.x; i < hi; i += 1024) {
        int row = r[i];
        int pos = atomicAdd(&cur[row >> shift], 1);
        rec[pos] = make_uint2((uint32)row, csrPACK(c[i], v[i]));
    }
}

// Pass B: one block per (matrix, bucket).  Bucket rows are block-exclusive -> LDS row
// counters; ELL scatter confined to a 64-96 KB L2-resident region.  Rows zero-padded
// to the next multiple of 8 so the spmm runs one uniform 8-wide loop (no serial tail).
__global__ __launch_bounds__(512) void fillB_kernel(
    const int* __restrict__ scanG, const uint2* __restrict__ rec,
    int* __restrict__ counts_all, uint32* __restrict__ ell) {
    __shared__ int cnt[512];
    int bx = (int)blockIdx.x;
    int m = bx / NBKT, b = bx - m * NBKT;
    int shift = c_shift[m];
    int rowlo = b << shift;
    int bklen = 1 << shift;
    for (int i = threadIdx.x; i < bklen; i += 512) cnt[i] = 0;
    __syncthreads();
    int lo = scanG[(m * NBKT + b) * PB];
    int hi = scanG[(m * NBKT + b + 1) * PB];   // b=195,m=3 -> scanG[SCANN] sentinel
    int cap = c_cap[m];
    uint32* ebase = ell + c_elloff[m];
    for (int i = lo + (int)threadIdx.x; i < hi; i += 512) {
        uint2 e = rec[i];
        int row = (int)e.x;
        int pos = atomicAdd(&cnt[row - rowlo], 1);
        ebase[(size_t)row * cap + pos] = e.y;
    }
    __syncthreads();
    int nrows_b = c_nrows[m] - rowlo;
    if (nrows_b > bklen) nrows_b = bklen;
    int* counts = counts_all + c_cntoff[m];
    for (int i = threadIdx.x; i < nrows_b; i += 512) {
        int ci = cnt[i];
        counts[rowlo + i] = ci;
        int pad = (ci + 7) & ~7;               // <= cap (cap is a multiple of 8)
        uint32* erow = ebase + (size_t)(rowlo + i) * cap;
        for (int j = ci; j < pad; j++) erow[j] = 0;   // exact no-op entries
    }
}

// ---------------- fused: fp32->bf16 cast of pois + softmax of the attention vecs ----------------
__global__ __launch_bounds__(256) void cast_soft_kernel(
    const float* __restrict__ src, uint32* __restrict__ dst,
    const float* __restrict__ adi, const float* __restrict__ amv,
    float* __restrict__ w) {
    int bx = (int)blockIdx.x;
    if (bx < 25000) {   // 25000*256 == NPOI*64 exactly
        int i = bx * 256 + (int)threadIdx.x;
        float2 f = *(const float2*)(src + (size_t)i * 2);
        dst[i] = bfPACK(f.x, f.y);
        return;
    }
    if (threadIdx.x == 0) {
        for (int b = 0; b < 2; b++) {
            const float* a = b ? amv : adi;
            float m = a[0];
            for (int l = 1; l < 4; l++) m = fmaxf(m, a[l]);
            float e[4]; float s = 0.f;
            for (int l = 0; l < 4; l++) { e[l] = __expf(a[l] - m); s += e[l]; }
            for (int l = 0; l < 4; l++) w[b * 4 + l] = e[l] / s;
        }
    }
}

// ---- 8-FMA helper: one scalar entry value v against a 16B (8 bf16) operand slice ----
__device__ __forceinline__ void fma8(float2& a0, float2& a1, float2& a2, float2& a3,
                                     float v, uint4 u) {
    a0.x = fmaf(v, bfLO(u.x), a0.x); a0.y = fmaf(v, bfHI(u.x), a0.y);
    a1.x = fmaf(v, bfLO(u.y), a1.x); a1.y = fmaf(v, bfHI(u.y), a1.y);
    a2.x = fmaf(v, bfLO(u.z), a2.x); a2.y = fmaf(v, bfHI(u.z), a2.y);
    a3.x = fmaf(v, bfLO(u.w), a3.x); a3.y = fmaf(v, bfHI(u.w), a3.y);
}

// ---------------- hop1 SpMM: y_bf[row] = A @ x_bf ----------------
// 16-lane group per row: lane t gathers uint4 (16B = 8 bf16) of the 256B operand row.
// Single uniform 8-wide loop over the zero-padded count (pad entries are exact no-ops).
template<int CAP>
__global__ __launch_bounds__(256) void spmm1_kernel(
    const int* __restrict__ counts, const uint32* __restrict__ ell,
    const uint32* __restrict__ xbf, uint32* __restrict__ ybf, int n_rows) {
    int row = (int)((blockIdx.x * blockDim.x + threadIdx.x) >> 4);
    int t   = (int)(threadIdx.x & 15);
    if (row >= n_rows) return;
    int pad = (counts[row] + 7) & ~7;
    const uint32* erow = ell + (size_t)row * CAP;
    float2 a0 = {0.f,0.f}, a1 = {0.f,0.f}, a2 = {0.f,0.f}, a3 = {0.f,0.f};
    for (int j = 0; j < pad; j += 8) {
        uint4 qa = *(const uint4*)(erow + j);
        uint4 qb = *(const uint4*)(erow + j + 4);
        uint4 u0 = *((const uint4*)(xbf + (size_t)csrCOL(qa.x) * 64) + t);
        uint4 u1 = *((const uint4*)(xbf + (size_t)csrCOL(qa.y) * 64) + t);
        uint4 u2 = *((const uint4*)(xbf + (size_t)csrCOL(qa.z) * 64) + t);
        uint4 u3 = *((const uint4*)(xbf + (size_t)csrCOL(qa.w) * 64) + t);
        uint4 u4 = *((const uint4*)(xbf + (size_t)csrCOL(qb.x) * 64) + t);
        uint4 u5 = *((const uint4*)(xbf + (size_t)csrCOL(qb.y) * 64) + t);
        uint4 u6 = *((const uint4*)(xbf + (size_t)csrCOL(qb.z) * 64) + t);
        uint4 u7 = *((const uint4*)(xbf + (size_t)csrCOL(qb.w) * 64) + t);
        fma8(a0,a1,a2,a3, csrVAL(qa.x), u0); fma8(a0,a1,a2,a3, csrVAL(qa.y), u1);
        fma8(a0,a1,a2,a3, csrVAL(qa.z), u2); fma8(a0,a1,a2,a3, csrVAL(qa.w), u3);
        fma8(a0,a1,a2,a3, csrVAL(qb.x), u4); fma8(a0,a1,a2,a3, csrVAL(qb.y), u5);
        fma8(a0,a1,a2,a3, csrVAL(qb.z), u6); fma8(a0,a1,a2,a3, csrVAL(qb.w), u7);
    }
    uint4 o;
    o.x = bfPACK(a0.x, a0.y); o.y = bfPACK(a1.x, a1.y);
    o.z = bfPACK(a2.x, a2.y); o.w = bfPACK(a3.x, a3.y);
    *((uint4*)(ybf + (size_t)row * 64) + t) = o;
}

// ---------------- hop2: xnew = relu(A@m)+xin, padded ELL ----------------
// MODE 0: write xnew (bf16) to xoutbf                       (layers 1,2)
// MODE 1: fused epi1: out = (w0+w4)*pois + w1*x1 + w2*x2 + w3*x3   (branch-0 layer 3)
// MODE 2: fused epi2: out += w5*x1 + w6*x2 + w7*x3                 (branch-1 layer 3)
// x3 stays in fp32 registers in MODE 1/2 (no bf16 round-trip) -> closer to reference.
template<int CAP, int MODE>
__global__ __launch_bounds__(256) void spmm2_kernel(
    const int* __restrict__ counts, const uint32* __restrict__ ell,
    const uint32* __restrict__ mbf, const uint32* __restrict__ xinbf,
    uint32* __restrict__ xoutbf, const uint32* __restrict__ x1bf,
    const float* __restrict__ pois, const float* __restrict__ w,
    float* __restrict__ outf, int n_rows) {
    int row = (int)((blockIdx.x * blockDim.x + threadIdx.x) >> 4);
    int t   = (int)(threadIdx.x & 15);
    if (row >= n_rows) return;
    int pad = (counts[row] + 7) & ~7;
    const uint32* erow = ell + (size_t)row * CAP;
    float2 a0 = {0.f,0.f}, a1 = {0.f,0.f}, a2 = {0.f,0.f}, a3 = {0.f,0.f};
    for (int j = 0; j < pad; j += 8) {
        uint4 qa = *(const uint4*)(erow + j);
        uint4 qb = *(const uint4*)(erow + j + 4);
        uint4 u0 = *((const uint4*)(mbf + (size_t)csrCOL(qa.x) * 64) + t);
        uint4 u1 = *((const uint4*)(mbf + (size_t)csrCOL(qa.y) * 64) + t);
        uint4 u2 = *((const uint4*)(mbf + (size_t)csrCOL(qa.z) * 64) + t);
        uint4 u3 = *((const uint4*)(mbf + (size_t)csrCOL(qa.w) * 64) + t);
        uint4 u4 = *((const uint4*)(mbf + (size_t)csrCOL(qb.x) * 64) + t);
        uint4 u5 = *((const uint4*)(mbf + (size_t)csrCOL(qb.y) * 64) + t);
        uint4 u6 = *((const uint4*)(mbf + (size_t)csrCOL(qb.z) * 64) + t);
        uint4 u7 = *((const uint4*)(mbf + (size_t)csrCOL(qb.w) * 64) + t);
        fma8(a0,a1,a2,a3, csrVAL(qa.x), u0); fma8(a0,a1,a2,a3, csrVAL(qa.y), u1);
        fma8(a0,a1,a2,a3, csrVAL(qa.z), u2); fma8(a0,a1,a2,a3, csrVAL(qa.w), u3);
        fma8(a0,a1,a2,a3, csrVAL(qb.x), u4); fma8(a0,a1,a2,a3, csrVAL(qb.y), u5);
        fma8(a0,a1,a2,a3, csrVAL(qb.z), u6); fma8(a0,a1,a2,a3, csrVAL(qb.w), u7);
    }
    uint4 ui = *((const uint4*)(xinbf + (size_t)row * 64) + t);   // x2 (or x_{l-1})
    float x2v[8] = { bfLO(ui.x), bfHI(ui.x), bfLO(ui.y), bfHI(ui.y),
                     bfLO(ui.z), bfHI(ui.z), bfLO(ui.w), bfHI(ui.w) };
    float x3v[8] = { fmaxf(a0.x,0.f)+x2v[0], fmaxf(a0.y,0.f)+x2v[1],
                     fmaxf(a1.x,0.f)+x2v[2], fmaxf(a1.y,0.f)+x2v[3],
                     fmaxf(a2.x,0.f)+x2v[4], fmaxf(a2.y,0.f)+x2v[5],
                     fmaxf(a3.x,0.f)+x2v[6], fmaxf(a3.y,0.f)+x2v[7] };
    if (MODE == 0) {
        uint4 o;
        o.x = bfPACK(x3v[0], x3v[1]); o.y = bfPACK(x3v[2], x3v[3]);
        o.z = bfPACK(x3v[4], x3v[5]); o.w = bfPACK(x3v[6], x3v[7]);
        *((uint4*)(xoutbf + (size_t)row * 64) + t) = o;
    } else {
        uint4 u1v = *((const uint4*)(x1bf + (size_t)row * 64) + t);
        float x1v[8] = { bfLO(u1v.x), bfHI(u1v.x), bfLO(u1v.y), bfHI(u1v.y),
                         bfLO(u1v.z), bfHI(u1v.z), bfLO(u1v.w), bfHI(u1v.w) };
        float* op = outf + (size_t)row * 128 + t * 8;
        float4 o0, o1;
        if (MODE == 1) {
            float w04 = w[0] + w[4];
            const float* pp = pois + (size_t)row * 128 + t * 8;
            float4 p0 = ((const float4*)pp)[0], p1 = ((const float4*)pp)[1];
            o0.x = w04*p0.x + w[1]*x1v[0] + w[2]*x2v[0] + w[3]*x3v[0];
            o0.y = w04*p0.y + w[1]*x1v[1] + w[2]*x2v[1] + w[3]*x3v[1];
            o0.z = w04*p0.z + w[1]*x1v[2] + w[2]*x2v[2] + w[3]*x3v[2];
            o0.w = w04*p0.w + w[1]*x1v[3] + w[2]*x2v[3] + w[3]*x3v[3];
            o1.x = w04*p1.x + w[1]*x1v[4] + w[2]*x2v[4] + w[3]*x3v[4];
            o1.y = w04*p1.y + w[1]*x1v[5] + w[2]*x2v[5] + w[3]*x3v[5];
            o1.z = w04*p1.z + w[1]*x1v[6] + w[2]*x2v[6] + w[3]*x3v[6];
            o1.w = w04*p1.w + w[1]*x1v[7] + w[2]*x2v[7] + w[3]*x3v[7];
        } else {
            float4 p0 = ((const float4*)op)[0], p1 = ((const float4*)op)[1];
            o0.x = p0.x + w[5]*x1v[0] + w[6]*x2v[0] + w[7]*x3v[0];
            o0.y = p0.y + w[5]*x1v[1] + w[6]*x2v[1] + w[7]*x3v[1];
            o0.z = p0.z + w[5]*x1v[2] + w[6]*x2v[2] + w[7]*x3v[2];
            o0.w = p0.w + w[5]*x1v[3] + w[6]*x2v[3] + w[7]*x3v[3];
            o1.x = p1.x + w[5]*x1v[4] + w[6]*x2v[4] + w[7]*x3v[4];
            o1.y = p1.y + w[5]*x1v[5] + w[6]*x2v[5] + w[7]*x3v[5];
            o1.z = p1.z + w[5]*x1v[6] + w[6]*x2v[6] + w[7]*x3v[6];
            o1.w = p1.w + w[5]*x1v[7] + w[6]*x2v[7] + w[7]*x3v[7];
        }
        ((float4*)op)[0] = o0;
        ((float4*)op)[1] = o1;
    }
}

extern "C" void kernel_launch(void* const* d_in, const int* in_sizes, int n_in,
                              void* d_out, int out_size, void* d_ws, size_t ws_size,
                              hipStream_t stream) {
    const float* pois = (const float*)d_in[0];
    const int*   rows_in[4] = { (const int*)d_in[1], (const int*)d_in[4],
                                (const int*)d_in[7], (const int*)d_in[10] };
    const int*   cols_in[4] = { (const int*)d_in[2], (const int*)d_in[5],
                                (const int*)d_in[8], (const int*)d_in[11] };
    const float* vals_in[4] = { (const float*)d_in[3], (const float*)d_in[6],
                                (const float*)d_in[9], (const float*)d_in[12] };
    const float* attn_di = (const float*)d_in[13];
    const float* attn_mv = (const float*)d_in[14];
    float* out = (float*)d_out;

    const int cnt_off[4] = { 0, NEDGE, NEDGE + NPOI, NEDGE + NPOI + NUSER };
    const long long ell_off[4] = { 0, 3200000, 8000000, 11200000 };
    const int NTOT = NEDGE + NPOI + NUSER + NPOI;  // 300000

    // -------- workspace carve-up (~182 MB, unchanged from round 11) --------
    char* p = (char*)d_ws;
    float*  wsoft      = (float*)p;  p += 256;
    int*    counts_all = (int*)p;    p += (size_t)NTOT * 4;
    p = (char*)(((size_t)p + 255) & ~255ull);
    int*    scanG      = (int*)p;    p += (size_t)(SCANN + 64) * 4;  // 50177 + pad
    p = (char*)(((size_t)p + 255) & ~255ull);
    uint32* ell        = (uint32*)p; p += (size_t)16000000 * 4;     // 64 MB ELL
    uint32* mbf        = (uint32*)p; p += (size_t)NEDGE * 64 * 4;   // 12.8 MB
    uint32* poisbf     = (uint32*)p; p += (size_t)NPOI * 64 * 4;    // 25.6 MB
    uint32* xl[3];
    for (int l = 0; l < 3; l++) { xl[l] = (uint32*)p; p += (size_t)NPOI * 64 * 4; }
    // records (32 MB) alias xl[0..1] (51.2 MB): consumed by fillB before spmm writes xl.
    uint2* rec = (uint2*)xl[0];
    (void)ws_size; (void)out_size; (void)n_in; (void)in_sizes;

    // -------- ELL build: hist -> scan -> scatter-sort -> bucket fill (+pad) --------
    histH_kernel<<<dim3(PB, 4), 1024, 0, stream>>>(
        rows_in[0], rows_in[1], rows_in[2], rows_in[3], scanG);
    scan_kernel<<<1, 256, 0, stream>>>(scanG);
    scatS_kernel<<<dim3(PB, 4), 1024, 0, stream>>>(
        rows_in[0], rows_in[1], rows_in[2], rows_in[3],
        cols_in[0], cols_in[1], cols_in[2], cols_in[3],
        vals_in[0], vals_in[1], vals_in[2], vals_in[3],
        scanG, rec);
    fillB_kernel<<<4 * NBKT, 512, 0, stream>>>(scanG, rec, counts_all, ell);

    // -------- fused cast(pois->bf16) + softmax --------
    cast_soft_kernel<<<25000 + 1, 256, 0, stream>>>(pois, poisbf, attn_di, attn_mv, wsoft);

    // -------- two branches, 3 layers each; epilogue fused into layer-3 spmm2 --------
    for (int br = 0; br < 2; br++) {
        int m1i = br ? 2 : 0;   // up  : tar   (50k rows, CAP 64)
        int m2i = br ? 3 : 1;   // pu  : src   (100k rows, CAP 48)
        const int* cn1 = counts_all + cnt_off[m1i];
        const int* cn2 = counts_all + cnt_off[m2i];
        const uint32* el1 = ell + ell_off[m1i];
        const uint32* el2 = ell + ell_off[m2i];
        const int n1 = 50000;  // NEDGE == NUSER
        const uint32* xcur = poisbf;
        for (int l = 1; l <= NL; l++) {
            spmm1_kernel<64><<<ceil_div(n1, 16), 256, 0, stream>>>(cn1, el1, xcur, mbf, n1);
            if (l < NL) {
                spmm2_kernel<48, 0><<<ceil_div(NPOI, 16), 256, 0, stream>>>(
                    cn2, el2, mbf, xcur, xl[l - 1], nullptr, nullptr, wsoft, nullptr, NPOI);
                xcur = xl[l - 1];
            } else if (br == 0) {
                spmm2_kernel<48, 1><<<ceil_div(NPOI, 16), 256, 0, stream>>>(
                    cn2, el2, mbf, xcur, nullptr, xl[0], pois, wsoft, out, NPOI);
            } else {
                spmm2_kernel<48, 2><<<ceil_div(NPOI, 16), 256, 0, stream>>>(
                    cn2, el2, mbf, xcur, nullptr, xl[0], nullptr, wsoft, out, NPOI);
            }
        }
    }
}